// Round 1
// baseline (1314.657 us; speedup 1.0000x reference)
//
#include <hip/hip_runtime.h>
#include <math.h>

// ---------------------------------------------------------------------------
// ManifoldNet SPD network, fused in log-domain.
//
// reference does: 10x [ logm -> conv(softmax w) -> symmetrize -> expm ], with
// identity-padding between the later layers. expm/logm pairs cancel;
// logm(identity) = 0, so padding becomes zero-padding in log-domain.
// We therefore do: logm(x) once -> 10 convs (+5 zero-pads) on the 6 unique
// components of the symmetric log field -> expm once.
// ---------------------------------------------------------------------------

#define DEVFN __device__ __forceinline__

// One Jacobi rotation for a 3x3 symmetric matrix (NR convention, V columns
// are eigenvectors, A = V diag V^T). p,q must be compile-time constants at
// the call sites so everything stays in registers.
DEVFN void jrot(float A[3][3], float V[3][3], int p, int q) {
    float apq = A[p][q];
    if (fabsf(apq) < 1e-30f) return;
    float app = A[p][p], aqq = A[q][q];
    float tau = (aqq - app) / (2.0f * apq);
    float t = copysignf(1.0f, tau) / (fabsf(tau) + sqrtf(1.0f + tau * tau));
    float c = rsqrtf(1.0f + t * t);
    float s = t * c;
    int r = 3 - p - q;
    float arp = A[r][p], arq = A[r][q];
    A[p][p] = app - t * apq;
    A[q][q] = aqq + t * apq;
    A[p][q] = 0.0f; A[q][p] = 0.0f;
    A[r][p] = c * arp - s * arq; A[p][r] = A[r][p];
    A[r][q] = s * arp + c * arq; A[q][r] = A[r][q];
#pragma unroll
    for (int i = 0; i < 3; ++i) {
        float vip = V[i][p], viq = V[i][q];
        V[i][p] = c * vip - s * viq;
        V[i][q] = s * vip + c * viq;
    }
}

DEVFN void eigh3(float A[3][3], float V[3][3]) {
    V[0][0] = 1.f; V[0][1] = 0.f; V[0][2] = 0.f;
    V[1][0] = 0.f; V[1][1] = 1.f; V[1][2] = 0.f;
    V[2][0] = 0.f; V[2][1] = 0.f; V[2][2] = 1.f;
#pragma unroll
    for (int s = 0; s < 6; ++s) {
        jrot(A, V, 0, 1);
        jrot(A, V, 0, 2);
        jrot(A, V, 1, 2);
    }
}

// x: [n,3,3] SPD (f32). out: planar [6][n], comps (00,01,02,11,12,22).
__global__ void logm_k(const float* __restrict__ x, float* __restrict__ out, int n) {
    int i = blockIdx.x * blockDim.x + threadIdx.x;
    if (i >= n) return;
    const float* m = x + (size_t)i * 9;
    float a01 = 0.5f * (m[1] + m[3]);
    float a02 = 0.5f * (m[2] + m[6]);
    float a12 = 0.5f * (m[5] + m[7]);
    float A[3][3] = {{m[0], a01, a02}, {a01, m[4], a12}, {a02, a12, m[8]}};
    float V[3][3];
    eigh3(A, V);
    float d0 = logf(fmaxf(A[0][0], 1e-30f));
    float d1 = logf(fmaxf(A[1][1], 1e-30f));
    float d2 = logf(fmaxf(A[2][2], 1e-30f));
    float L00 = V[0][0]*d0*V[0][0] + V[0][1]*d1*V[0][1] + V[0][2]*d2*V[0][2];
    float L01 = V[0][0]*d0*V[1][0] + V[0][1]*d1*V[1][1] + V[0][2]*d2*V[1][2];
    float L02 = V[0][0]*d0*V[2][0] + V[0][1]*d1*V[2][1] + V[0][2]*d2*V[2][2];
    float L11 = V[1][0]*d0*V[1][0] + V[1][1]*d1*V[1][1] + V[1][2]*d2*V[1][2];
    float L12 = V[1][0]*d0*V[2][0] + V[1][1]*d1*V[2][1] + V[1][2]*d2*V[2][2];
    float L22 = V[2][0]*d0*V[2][0] + V[2][1]*d1*V[2][1] + V[2][2]*d2*V[2][2];
    out[0 * (size_t)n + i] = L00;
    out[1 * (size_t)n + i] = L01;
    out[2 * (size_t)n + i] = L02;
    out[3 * (size_t)n + i] = L11;
    out[4 * (size_t)n + i] = L12;
    out[5 * (size_t)n + i] = L22;
}

// Lp: planar [6][n] symmetric log field -> out [n,3,3] f32 (expm).
__global__ void expm_k(const float* __restrict__ Lp, float* __restrict__ out, int n) {
    int i = blockIdx.x * blockDim.x + threadIdx.x;
    if (i >= n) return;
    float a00 = Lp[0 * (size_t)n + i];
    float a01 = Lp[1 * (size_t)n + i];
    float a02 = Lp[2 * (size_t)n + i];
    float a11 = Lp[3 * (size_t)n + i];
    float a12 = Lp[4 * (size_t)n + i];
    float a22 = Lp[5 * (size_t)n + i];
    float A[3][3] = {{a00, a01, a02}, {a01, a11, a12}, {a02, a12, a22}};
    float V[3][3];
    eigh3(A, V);
    float e0 = expf(A[0][0]);
    float e1 = expf(A[1][1]);
    float e2 = expf(A[2][2]);
    float m00 = V[0][0]*e0*V[0][0] + V[0][1]*e1*V[0][1] + V[0][2]*e2*V[0][2];
    float m01 = V[0][0]*e0*V[1][0] + V[0][1]*e1*V[1][1] + V[0][2]*e2*V[1][2];
    float m02 = V[0][0]*e0*V[2][0] + V[0][1]*e1*V[2][1] + V[0][2]*e2*V[2][2];
    float m11 = V[1][0]*e0*V[1][0] + V[1][1]*e1*V[1][1] + V[1][2]*e2*V[1][2];
    float m12 = V[1][0]*e0*V[2][0] + V[1][1]*e1*V[2][1] + V[1][2]*e2*V[2][2];
    float m22 = V[2][0]*e0*V[2][0] + V[2][1]*e1*V[2][1] + V[2][2]*e2*V[2][2];
    float* o = out + (size_t)i * 9;
    o[0] = m00; o[1] = m01; o[2] = m02;
    o[3] = m01; o[4] = m11; o[5] = m12;
    o[6] = m02; o[7] = m12; o[8] = m22;
}

// per-co softmax over n = Ci*K*K weights
__global__ void softmax_k(const float* __restrict__ w, float* __restrict__ wn,
                          int Co, int n) {
    int co = blockIdx.x * blockDim.x + threadIdx.x;
    if (co >= Co) return;
    const float* p = w + (size_t)co * n;
    float mx = -1e30f;
    for (int i = 0; i < n; ++i) mx = fmaxf(mx, p[i]);
    float s = 0.f;
    for (int i = 0; i < n; ++i) s += expf(p[i] - mx);
    float inv = 1.0f / s;
    for (int i = 0; i < n; ++i) wn[(size_t)co * n + i] = expf(p[i] - mx) * inv;
}

// Direct VALID conv on planar [6][B][C][H][W] log field.
// grid: (ceil(Wo/16), ceil(Ho/16), B*Co), block (16,16).
__global__ void conv_log(const float* __restrict__ in, float* __restrict__ out,
                         const float* __restrict__ wn,
                         int B, int Ci, int Co, int Hi, int Wi, int K) {
    int Ho = Hi - K + 1, Wo = Wi - K + 1;
    __shared__ float wl[160];
    int nw = Ci * K * K;
    int tid = threadIdx.y * blockDim.x + threadIdx.x;
    int bz = blockIdx.z;
    int co = bz % Co, b = bz / Co;
    for (int i = tid; i < nw; i += 256) wl[i] = wn[(size_t)co * nw + i];
    __syncthreads();
    int wo = blockIdx.x * 16 + threadIdx.x;
    int ho = blockIdx.y * 16 + threadIdx.y;
    if (wo >= Wo || ho >= Ho) return;
    const size_t planeI = (size_t)B * Ci * Hi * Wi;
    const size_t planeO = (size_t)B * Co * Ho * Wo;
    float acc[6] = {0.f, 0.f, 0.f, 0.f, 0.f, 0.f};
    for (int ci = 0; ci < Ci; ++ci) {
        const float* ibase = in + ((size_t)(b * Ci + ci) * Hi + ho) * Wi + wo;
        const float* wbase = wl + ci * K * K;
        for (int kh = 0; kh < K; ++kh) {
            for (int kw = 0; kw < K; ++kw) {
                float w = wbase[kh * K + kw];
                const float* p = ibase + (size_t)kh * Wi + kw;
#pragma unroll
                for (int c = 0; c < 6; ++c)
                    acc[c] = fmaf(w, p[c * planeI], acc[c]);
            }
        }
    }
    size_t oidx = ((size_t)(b * Co + co) * Ho + ho) * Wo + wo;
#pragma unroll
    for (int c = 0; c < 6; ++c) out[c * planeO + oidx] = acc[c];
}

// zero-pad in log-domain: out (H+p)x(W+p); out[r,j] = in[r-p, j-p] iff
// p <= r < H and p <= j < W (matches reference _pad_identity: last p rows/cols
// of the source are dropped, border is identity -> 0 in log-domain).
__global__ void pad_zero(const float* __restrict__ in, float* __restrict__ out,
                         int B, int C, int H, int W, int p) {
    int Hn = H + p, Wn = W + p;
    size_t n = (size_t)6 * B * C * Hn * Wn;
    size_t i = (size_t)blockIdx.x * blockDim.x + threadIdx.x;
    if (i >= n) return;
    int j = (int)(i % Wn); size_t t = i / Wn;
    int r = (int)(t % Hn); t /= Hn;
    size_t cb = t; // comp*B*C + bc
    float v = 0.0f;
    if (r >= p && r < H && j >= p && j < W)
        v = in[cb * (size_t)H * W + (size_t)(r - p) * W + (j - p)];
    out[i] = v;
}

extern "C" void kernel_launch(void* const* d_in, const int* in_sizes, int n_in,
                              void* d_out, int out_size, void* d_ws, size_t ws_size,
                              hipStream_t stream) {
    const float* x = (const float*)d_in[0];
    const float* w[10];
    for (int i = 0; i < 10; ++i) w[i] = (const float*)d_in[1 + i];
    float* out = (float*)d_out;
    float* ws = (float*)d_ws;

    static const int CiA[10]  = {1, 4, 8, 16, 16, 8, 16, 16, 8, 4};
    static const int CoA[10]  = {4, 8, 16, 16, 8, 16, 16, 8, 4, 1};
    static const int KA[10]   = {3, 3, 3, 2, 2, 2, 2, 3, 3, 3};
    static const int PADA[10] = {0, 0, 0, 0, 2, 2, 4, 4, 4, 0};

    int wnoff[11]; wnoff[0] = 0;
    for (int l = 0; l < 10; ++l) wnoff[l + 1] = wnoff[l] + CoA[l] * CiA[l] * KA[l] * KA[l];

    float* wn = ws;                       // 8192 floats reserved for weights
    const size_t BUF = 6900000;           // floats per ping-pong buffer (~27.6 MB)
    float* bufA = ws + 8192;
    float* bufB = bufA + BUF;

    for (int l = 0; l < 10; ++l)
        softmax_k<<<1, 64, 0, stream>>>(w[l], wn + wnoff[l], CoA[l], CiA[l] * KA[l] * KA[l]);

    const int Bn = 8;
    const int NMAT = 8 * 96 * 96;         // 73728 input matrices
    logm_k<<<(NMAT + 255) / 256, 256, 0, stream>>>(x, bufA, NMAT);

    float* cur = bufA;
    float* nxt = bufB;
    int H = 96, W = 96;
    for (int l = 0; l < 10; ++l) {
        int K = KA[l], Ci = CiA[l], Co = CoA[l];
        int Ho = H - K + 1, Wo = W - K + 1;
        dim3 blk(16, 16);
        dim3 grd((Wo + 15) / 16, (Ho + 15) / 16, Bn * Co);
        conv_log<<<grd, blk, 0, stream>>>(cur, nxt, wn + wnoff[l], Bn, Ci, Co, H, W, K);
        { float* t = cur; cur = nxt; nxt = t; }
        H = Ho; W = Wo;
        if (PADA[l]) {
            int p = PADA[l];
            size_t n = (size_t)6 * Bn * Co * (H + p) * (W + p);
            pad_zero<<<(unsigned)((n + 255) / 256), 256, 0, stream>>>(cur, nxt, Bn, Co, H, W, p);
            { float* t = cur; cur = nxt; nxt = t; }
            H += p; W += p;
        }
    }

    expm_k<<<(NMAT + 255) / 256, 256, 0, stream>>>(cur, out, NMAT);
}

// Round 2
// 599.506 us; speedup vs baseline: 2.1929x; 2.1929x over previous
//
#include <hip/hip_runtime.h>
#include <math.h>

// ---------------------------------------------------------------------------
// ManifoldNet SPD network, fused in log-domain.
// logm(x) once -> 10 convs (zero-pad fused into staging) on the 6 unique
// components of the symmetric log field (treated as batch) -> expm once.
// Conv v2: LDS-tiled, input read once per spatial tile for ALL Co.
// ---------------------------------------------------------------------------

#define DEVFN __device__ __forceinline__

DEVFN void jrot(float A[3][3], float V[3][3], int p, int q) {
    float apq = A[p][q];
    if (fabsf(apq) < 1e-30f) return;
    float app = A[p][p], aqq = A[q][q];
    float tau = (aqq - app) / (2.0f * apq);
    float t = copysignf(1.0f, tau) / (fabsf(tau) + sqrtf(1.0f + tau * tau));
    float c = rsqrtf(1.0f + t * t);
    float s = t * c;
    int r = 3 - p - q;
    float arp = A[r][p], arq = A[r][q];
    A[p][p] = app - t * apq;
    A[q][q] = aqq + t * apq;
    A[p][q] = 0.0f; A[q][p] = 0.0f;
    A[r][p] = c * arp - s * arq; A[p][r] = A[r][p];
    A[r][q] = s * arp + c * arq; A[q][r] = A[r][q];
#pragma unroll
    for (int i = 0; i < 3; ++i) {
        float vip = V[i][p], viq = V[i][q];
        V[i][p] = c * vip - s * viq;
        V[i][q] = s * vip + c * viq;
    }
}

DEVFN void eigh3(float A[3][3], float V[3][3]) {
    V[0][0] = 1.f; V[0][1] = 0.f; V[0][2] = 0.f;
    V[1][0] = 0.f; V[1][1] = 1.f; V[1][2] = 0.f;
    V[2][0] = 0.f; V[2][1] = 0.f; V[2][2] = 1.f;
#pragma unroll
    for (int s = 0; s < 6; ++s) {
        jrot(A, V, 0, 1);
        jrot(A, V, 0, 2);
        jrot(A, V, 1, 2);
    }
}

// x: [n,3,3] SPD (f32). out: planar [6][n], comps (00,01,02,11,12,22).
__global__ void logm_k(const float* __restrict__ x, float* __restrict__ out, int n) {
    int i = blockIdx.x * blockDim.x + threadIdx.x;
    if (i >= n) return;
    const float* m = x + (size_t)i * 9;
    float a01 = 0.5f * (m[1] + m[3]);
    float a02 = 0.5f * (m[2] + m[6]);
    float a12 = 0.5f * (m[5] + m[7]);
    float A[3][3] = {{m[0], a01, a02}, {a01, m[4], a12}, {a02, a12, m[8]}};
    float V[3][3];
    eigh3(A, V);
    float d0 = logf(fmaxf(A[0][0], 1e-30f));
    float d1 = logf(fmaxf(A[1][1], 1e-30f));
    float d2 = logf(fmaxf(A[2][2], 1e-30f));
    float L00 = V[0][0]*d0*V[0][0] + V[0][1]*d1*V[0][1] + V[0][2]*d2*V[0][2];
    float L01 = V[0][0]*d0*V[1][0] + V[0][1]*d1*V[1][1] + V[0][2]*d2*V[1][2];
    float L02 = V[0][0]*d0*V[2][0] + V[0][1]*d1*V[2][1] + V[0][2]*d2*V[2][2];
    float L11 = V[1][0]*d0*V[1][0] + V[1][1]*d1*V[1][1] + V[1][2]*d2*V[1][2];
    float L12 = V[1][0]*d0*V[2][0] + V[1][1]*d1*V[2][1] + V[1][2]*d2*V[2][2];
    float L22 = V[2][0]*d0*V[2][0] + V[2][1]*d1*V[2][1] + V[2][2]*d2*V[2][2];
    out[0 * (size_t)n + i] = L00;
    out[1 * (size_t)n + i] = L01;
    out[2 * (size_t)n + i] = L02;
    out[3 * (size_t)n + i] = L11;
    out[4 * (size_t)n + i] = L12;
    out[5 * (size_t)n + i] = L22;
}

__global__ void expm_k(const float* __restrict__ Lp, float* __restrict__ out, int n) {
    int i = blockIdx.x * blockDim.x + threadIdx.x;
    if (i >= n) return;
    float a00 = Lp[0 * (size_t)n + i];
    float a01 = Lp[1 * (size_t)n + i];
    float a02 = Lp[2 * (size_t)n + i];
    float a11 = Lp[3 * (size_t)n + i];
    float a12 = Lp[4 * (size_t)n + i];
    float a22 = Lp[5 * (size_t)n + i];
    float A[3][3] = {{a00, a01, a02}, {a01, a11, a12}, {a02, a12, a22}};
    float V[3][3];
    eigh3(A, V);
    float e0 = expf(A[0][0]);
    float e1 = expf(A[1][1]);
    float e2 = expf(A[2][2]);
    float m00 = V[0][0]*e0*V[0][0] + V[0][1]*e1*V[0][1] + V[0][2]*e2*V[0][2];
    float m01 = V[0][0]*e0*V[1][0] + V[0][1]*e1*V[1][1] + V[0][2]*e2*V[1][2];
    float m02 = V[0][0]*e0*V[2][0] + V[0][1]*e1*V[2][1] + V[0][2]*e2*V[2][2];
    float m11 = V[1][0]*e0*V[1][0] + V[1][1]*e1*V[1][1] + V[1][2]*e2*V[1][2];
    float m12 = V[1][0]*e0*V[2][0] + V[1][1]*e1*V[2][1] + V[1][2]*e2*V[2][2];
    float m22 = V[2][0]*e0*V[2][0] + V[2][1]*e1*V[2][1] + V[2][2]*e2*V[2][2];
    float* o = out + (size_t)i * 9;
    o[0] = m00; o[1] = m01; o[2] = m02;
    o[3] = m01; o[4] = m11; o[5] = m12;
    o[6] = m02; o[7] = m12; o[8] = m22;
}

// One kernel for all 10 layer softmaxes: block l = layer l, thread co.
struct WP {
    const float* src[10];
    float* dst[10];
    int Co[10];
    int n[10];
};
__global__ void softmax_all(WP wp) {
    int l = blockIdx.x;
    int co = threadIdx.x;
    if (co >= wp.Co[l]) return;
    int n = wp.n[l];
    const float* src = wp.src[l] + (size_t)co * n;
    float* dst = wp.dst[l] + (size_t)co * n;
    float mx = -1e30f;
    for (int i = 0; i < n; ++i) mx = fmaxf(mx, src[i]);
    float s = 0.f;
    for (int i = 0; i < n; ++i) s += expf(src[i] - mx);
    float inv = 1.0f / s;
    for (int i = 0; i < n; ++i) dst[i] = expf(src[i] - mx) * inv;
}

// ---------------------------------------------------------------------------
// LDS-tiled direct conv on planar [48][C][H][W] log field, with fused PRE-pad
// (virtual zero-padding of p rows/cols at top-left; rows >= Hin are zero too,
// matching the reference's identity padding semantics in log-domain).
// Block 16x16, each thread computes P=3 x-adjacent pixels for ALL Co.
// ---------------------------------------------------------------------------
template<int CI, int CO, int K>
__global__ __launch_bounds__(256)
void conv_tile(const float* __restrict__ in, float* __restrict__ out,
               const float* __restrict__ wn, int Hin, int Win, int pad) {
    constexpr int P = 3, TH = 16, TW = 48;
    constexpr int CC = (CI > 8) ? 8 : CI;
    constexpr int THI = TH + K - 1;
    constexpr int TWI = TW + K - 1;
    constexpr int ROWW = 52;                  // padded LDS row (floats)

    __shared__ float wl[CI * K * CO * 4];
    __shared__ float itile[CC][THI][ROWW];

    const int tx = threadIdx.x, ty = threadIdx.y;
    const int tid = ty * 16 + tx;
    const int Hv = Hin + pad, Wv = Win + pad;
    const int Ho = Hv - K + 1, Wo = Wv - K + 1;
    const int nb = blockIdx.z;
    const int gy0 = blockIdx.y * TH;
    const int gx0 = blockIdx.x * TW;

    // stage softmaxed weights: wn [co][ci][kh][kw] -> wl[ci][kh][co][4]
    for (int idx = tid; idx < CO * CI * K * K; idx += 256) {
        int co = idx / (CI * K * K);
        int rem = idx - co * (CI * K * K);
        int ci = rem / (K * K);
        int r2 = rem - ci * (K * K);
        int kh = r2 / K;
        int kw = r2 - kh * K;
        wl[((ci * K + kh) * CO + co) * 4 + kw] = wn[idx];
    }

    float acc[CO][P];
#pragma unroll
    for (int co = 0; co < CO; ++co)
#pragma unroll
        for (int p = 0; p < P; ++p) acc[co][p] = 0.f;

    const int oy = gy0 + ty;
    const int x0 = gx0 + tx * P;

    for (int c0 = 0; c0 < CI; c0 += CC) {
        __syncthreads();
        // stage CC channels of the (virtually padded) input tile
        for (int cc = 0; cc < CC; ++cc) {
            const float* ibase = in + ((size_t)(nb * CI + c0 + cc) * Hin) * Win;
            for (int r = ty; r < THI; r += 16) {
                int gy = gy0 + r;
                int sy = gy - pad;
                bool yok = (gy >= pad) && (gy < Hin);
                for (int c = tx; c < TWI; c += 16) {
                    int gx = gx0 + c;
                    float v = 0.f;
                    if (yok && gx >= pad && gx < Win)
                        v = ibase[(size_t)sy * Win + (gx - pad)];
                    itile[cc][r][c] = v;
                }
            }
        }
        __syncthreads();
        for (int cc = 0; cc < CC; ++cc) {
            const int ci = c0 + cc;
#pragma unroll
            for (int kh = 0; kh < K; ++kh) {
                float rv[P + K - 1];
#pragma unroll
                for (int j = 0; j < P + K - 1; ++j)
                    rv[j] = itile[cc][ty + kh][tx * P + j];
                const float* wb = &wl[(size_t)(ci * K + kh) * CO * 4];
#pragma unroll
                for (int co = 0; co < CO; ++co) {
                    float4 wv = *(const float4*)(wb + co * 4);
#pragma unroll
                    for (int kw = 0; kw < K; ++kw) {
                        float w = (kw == 0) ? wv.x : (kw == 1) ? wv.y : wv.z;
#pragma unroll
                        for (int p = 0; p < P; ++p)
                            acc[co][p] = fmaf(rv[p + kw], w, acc[co][p]);
                    }
                }
            }
        }
    }

    if (oy < Ho) {
#pragma unroll
        for (int co = 0; co < CO; ++co) {
            float* obase = out + ((size_t)(nb * CO + co) * Ho + oy) * Wo;
#pragma unroll
            for (int p = 0; p < P; ++p) {
                int x = x0 + p;
                if (x < Wo) obase[x] = acc[co][p];
            }
        }
    }
}

extern "C" void kernel_launch(void* const* d_in, const int* in_sizes, int n_in,
                              void* d_out, int out_size, void* d_ws, size_t ws_size,
                              hipStream_t stream) {
    const float* x = (const float*)d_in[0];
    float* out = (float*)d_out;
    float* ws = (float*)d_ws;

    static const int CiA[10]  = {1, 4, 8, 16, 16, 8, 16, 16, 8, 4};
    static const int CoA[10]  = {4, 8, 16, 16, 8, 16, 16, 8, 4, 1};
    static const int KA[10]   = {3, 3, 3, 2, 2, 2, 2, 3, 3, 3};
    static const int PREPAD[10] = {0, 0, 0, 0, 0, 2, 2, 4, 4, 4};

    int wnoff[11]; wnoff[0] = 0;
    for (int l = 0; l < 10; ++l)
        wnoff[l + 1] = wnoff[l] + CoA[l] * CiA[l] * KA[l] * KA[l];

    float* wn = ws;                       // softmaxed weights (< 8192 floats)
    const size_t BUF = 6900000;
    float* bufA = ws + 8192;
    float* bufB = bufA + BUF;

    // all 10 softmaxes in one kernel
    WP wp;
    for (int l = 0; l < 10; ++l) {
        wp.src[l] = (const float*)d_in[1 + l];
        wp.dst[l] = wn + wnoff[l];
        wp.Co[l] = CoA[l];
        wp.n[l] = CiA[l] * KA[l] * KA[l];
    }
    softmax_all<<<10, 64, 0, stream>>>(wp);

    const int Bn = 8;
    const int NB = 48;                    // 6 comps * 8 batch
    const int NMAT = 8 * 96 * 96;
    logm_k<<<(NMAT + 255) / 256, 256, 0, stream>>>(x, bufA, NMAT);

    float* cur = bufA;
    float* nxt = bufB;
    int H = 96, W = 96;                   // stored dims of cur

#define RUN_LAYER(L, CI_, CO_, K_)                                          \
    {                                                                       \
        int pad = PREPAD[L];                                                \
        int Hv = H + pad, Wv = W + pad;                                     \
        int Ho = Hv - K_ + 1, Wo = Wv - K_ + 1;                             \
        dim3 blk(16, 16);                                                   \
        dim3 grd((Wo + 47) / 48, (Ho + 15) / 16, NB);                       \
        conv_tile<CI_, CO_, K_><<<grd, blk, 0, stream>>>(                   \
            cur, nxt, wn + wnoff[L], H, W, pad);                            \
        { float* t = cur; cur = nxt; nxt = t; }                             \
        H = Ho; W = Wo;                                                     \
    }

    RUN_LAYER(0, 1, 4, 3)
    RUN_LAYER(1, 4, 8, 3)
    RUN_LAYER(2, 8, 16, 3)
    RUN_LAYER(3, 16, 16, 2)
    RUN_LAYER(4, 16, 8, 2)
    RUN_LAYER(5, 8, 16, 2)
    RUN_LAYER(6, 16, 16, 2)
    RUN_LAYER(7, 16, 8, 3)
    RUN_LAYER(8, 8, 4, 3)
    RUN_LAYER(9, 4, 1, 3)
#undef RUN_LAYER

    expm_k<<<(NMAT + 255) / 256, 256, 0, stream>>>(cur, out, NMAT);
}

// Round 3
// 395.628 us; speedup vs baseline: 3.3230x; 1.5153x over previous
//
#include <hip/hip_runtime.h>
#include <math.h>

// ---------------------------------------------------------------------------
// ManifoldNet SPD network, fused in log-domain.
// logm(x) once -> 10 convs (zero-pad fused into staging) on the 6 unique
// components of the symmetric log field (treated as batch) -> expm once.
// Conv v3: LDS input tile, weights via wave-uniform scalar loads (SGPR),
// 4 co x 2 px per thread -> no spills, high occupancy.
// ---------------------------------------------------------------------------

#define DEVFN __device__ __forceinline__

DEVFN void jrot(float A[3][3], float V[3][3], int p, int q) {
    float apq = A[p][q];
    if (fabsf(apq) < 1e-30f) return;
    float app = A[p][p], aqq = A[q][q];
    float tau = (aqq - app) / (2.0f * apq);
    float t = copysignf(1.0f, tau) / (fabsf(tau) + sqrtf(1.0f + tau * tau));
    float c = rsqrtf(1.0f + t * t);
    float s = t * c;
    int r = 3 - p - q;
    float arp = A[r][p], arq = A[r][q];
    A[p][p] = app - t * apq;
    A[q][q] = aqq + t * apq;
    A[p][q] = 0.0f; A[q][p] = 0.0f;
    A[r][p] = c * arp - s * arq; A[p][r] = A[r][p];
    A[r][q] = s * arp + c * arq; A[q][r] = A[r][q];
#pragma unroll
    for (int i = 0; i < 3; ++i) {
        float vip = V[i][p], viq = V[i][q];
        V[i][p] = c * vip - s * viq;
        V[i][q] = s * vip + c * viq;
    }
}

DEVFN void eigh3(float A[3][3], float V[3][3]) {
    V[0][0] = 1.f; V[0][1] = 0.f; V[0][2] = 0.f;
    V[1][0] = 0.f; V[1][1] = 1.f; V[1][2] = 0.f;
    V[2][0] = 0.f; V[2][1] = 0.f; V[2][2] = 1.f;
#pragma unroll
    for (int s = 0; s < 6; ++s) {
        jrot(A, V, 0, 1);
        jrot(A, V, 0, 2);
        jrot(A, V, 1, 2);
    }
}

// x: [n,3,3] SPD (f32). out: planar [6][n], comps (00,01,02,11,12,22).
__global__ void logm_k(const float* __restrict__ x, float* __restrict__ out, int n) {
    int i = blockIdx.x * blockDim.x + threadIdx.x;
    if (i >= n) return;
    const float* m = x + (size_t)i * 9;
    float a01 = 0.5f * (m[1] + m[3]);
    float a02 = 0.5f * (m[2] + m[6]);
    float a12 = 0.5f * (m[5] + m[7]);
    float A[3][3] = {{m[0], a01, a02}, {a01, m[4], a12}, {a02, a12, m[8]}};
    float V[3][3];
    eigh3(A, V);
    float d0 = logf(fmaxf(A[0][0], 1e-30f));
    float d1 = logf(fmaxf(A[1][1], 1e-30f));
    float d2 = logf(fmaxf(A[2][2], 1e-30f));
    float L00 = V[0][0]*d0*V[0][0] + V[0][1]*d1*V[0][1] + V[0][2]*d2*V[0][2];
    float L01 = V[0][0]*d0*V[1][0] + V[0][1]*d1*V[1][1] + V[0][2]*d2*V[1][2];
    float L02 = V[0][0]*d0*V[2][0] + V[0][1]*d1*V[2][1] + V[0][2]*d2*V[2][2];
    float L11 = V[1][0]*d0*V[1][0] + V[1][1]*d1*V[1][1] + V[1][2]*d2*V[1][2];
    float L12 = V[1][0]*d0*V[2][0] + V[1][1]*d1*V[2][1] + V[1][2]*d2*V[2][2];
    float L22 = V[2][0]*d0*V[2][0] + V[2][1]*d1*V[2][1] + V[2][2]*d2*V[2][2];
    out[0 * (size_t)n + i] = L00;
    out[1 * (size_t)n + i] = L01;
    out[2 * (size_t)n + i] = L02;
    out[3 * (size_t)n + i] = L11;
    out[4 * (size_t)n + i] = L12;
    out[5 * (size_t)n + i] = L22;
}

__global__ void expm_k(const float* __restrict__ Lp, float* __restrict__ out, int n) {
    int i = blockIdx.x * blockDim.x + threadIdx.x;
    if (i >= n) return;
    float a00 = Lp[0 * (size_t)n + i];
    float a01 = Lp[1 * (size_t)n + i];
    float a02 = Lp[2 * (size_t)n + i];
    float a11 = Lp[3 * (size_t)n + i];
    float a12 = Lp[4 * (size_t)n + i];
    float a22 = Lp[5 * (size_t)n + i];
    float A[3][3] = {{a00, a01, a02}, {a01, a11, a12}, {a02, a12, a22}};
    float V[3][3];
    eigh3(A, V);
    float e0 = expf(A[0][0]);
    float e1 = expf(A[1][1]);
    float e2 = expf(A[2][2]);
    float m00 = V[0][0]*e0*V[0][0] + V[0][1]*e1*V[0][1] + V[0][2]*e2*V[0][2];
    float m01 = V[0][0]*e0*V[1][0] + V[0][1]*e1*V[1][1] + V[0][2]*e2*V[1][2];
    float m02 = V[0][0]*e0*V[2][0] + V[0][1]*e1*V[2][1] + V[0][2]*e2*V[2][2];
    float m11 = V[1][0]*e0*V[1][0] + V[1][1]*e1*V[1][1] + V[1][2]*e2*V[1][2];
    float m12 = V[1][0]*e0*V[2][0] + V[1][1]*e1*V[2][1] + V[1][2]*e2*V[2][2];
    float m22 = V[2][0]*e0*V[2][0] + V[2][1]*e1*V[2][1] + V[2][2]*e2*V[2][2];
    float* o = out + (size_t)i * 9;
    o[0] = m00; o[1] = m01; o[2] = m02;
    o[3] = m01; o[4] = m11; o[5] = m12;
    o[6] = m02; o[7] = m12; o[8] = m22;
}

// One kernel for all 10 layer softmaxes: block l = layer l, thread co.
struct WP {
    const float* src[10];
    float* dst[10];
    int Co[10];
    int n[10];
};
__global__ void softmax_all(WP wp) {
    int l = blockIdx.x;
    int co = threadIdx.x;
    if (co >= wp.Co[l]) return;
    int n = wp.n[l];
    const float* src = wp.src[l] + (size_t)co * n;
    float* dst = wp.dst[l] + (size_t)co * n;
    float mx = -1e30f;
    for (int i = 0; i < n; ++i) mx = fmaxf(mx, src[i]);
    float s = 0.f;
    for (int i = 0; i < n; ++i) s += expf(src[i] - mx);
    float inv = 1.0f / s;
    for (int i = 0; i < n; ++i) dst[i] = expf(src[i] - mx) * inv;
}

// ---------------------------------------------------------------------------
// LDS-tiled direct conv on planar [48][C][H][W] log field with fused PRE-pad
// (virtual zero rows/cols: out-of-range of [pad, Hin) x [pad, Win) reads 0,
// matching reference identity padding in log-domain).
// Block 16x16. Thread: P=2 x-pixels, COT=4 output channels.
// gridDim.z = 48 * (CO/COT). Weights read with wave-uniform indices -> SGPR.
// ---------------------------------------------------------------------------
template<int CI, int CO, int K>
__global__ __launch_bounds__(256)
void conv_tile(const float* __restrict__ in, float* __restrict__ out,
               const float* __restrict__ wn, int Hin, int Win, int pad) {
    constexpr int COT = (CO < 4) ? CO : 4;
    constexpr int NG = CO / COT;
    constexpr int P = 2, TH = 16, TW = 32;
    constexpr int CC = (CI > 8) ? 8 : CI;
    constexpr int THI = TH + K - 1;
    constexpr int TWI = TW + K - 1;
    constexpr int ROWW = (TWI + 3) & ~3;

    __shared__ float itile[CC][THI][ROWW];

    const int tx = threadIdx.x, ty = threadIdx.y;
    const int tid = ty * 16 + tx;
    const int Hv = Hin + pad, Wv = Win + pad;
    const int Ho = Hv - K + 1, Wo = Wv - K + 1;
    const int bz = blockIdx.z;
    const int cog = bz % NG;          // wave-uniform co group
    const int nb = bz / NG;
    const int gy0 = blockIdx.y * TH;
    const int gx0 = blockIdx.x * TW;

    float acc[COT][P];
#pragma unroll
    for (int c2 = 0; c2 < COT; ++c2)
#pragma unroll
        for (int p = 0; p < P; ++p) acc[c2][p] = 0.f;

    const int oy = gy0 + ty;
    const int x0 = gx0 + tx * P;

    for (int c0 = 0; c0 < CI; c0 += CC) {
        __syncthreads();
        // stage CC channels of the (virtually padded) input tile
#pragma unroll
        for (int cc = 0; cc < CC; ++cc) {
            const float* ibase = in + ((size_t)(nb * CI + c0 + cc) * Hin) * Win;
            for (int idx = tid; idx < THI * TWI; idx += 256) {
                int r = idx / TWI;
                int c = idx - r * TWI;
                int gy = gy0 + r, gx = gx0 + c;
                float v = 0.f;
                if (gy >= pad && gy < Hin && gx >= pad && gx < Win)
                    v = ibase[(size_t)(gy - pad) * Win + (gx - pad)];
                itile[cc][r][c] = v;
            }
        }
        __syncthreads();
#pragma unroll
        for (int cc = 0; cc < CC; ++cc) {
            const int ci = c0 + cc;
#pragma unroll
            for (int kh = 0; kh < K; ++kh) {
                float2 u0 = *(const float2*)&itile[cc][ty + kh][tx * P];
                float2 u1 = *(const float2*)&itile[cc][ty + kh][tx * P + 2];
                float rv[4] = {u0.x, u0.y, u1.x, u1.y};
#pragma unroll
                for (int c2 = 0; c2 < COT; ++c2) {
                    const int co = cog * COT + c2;
                    const float* wb = wn + ((size_t)co * CI + ci) * (K * K) + kh * K;
#pragma unroll
                    for (int kw = 0; kw < K; ++kw) {
                        float w = wb[kw];   // uniform -> s_load, SGPR operand
#pragma unroll
                        for (int p = 0; p < P; ++p)
                            acc[c2][p] = fmaf(rv[p + kw], w, acc[c2][p]);
                    }
                }
            }
        }
    }

    if (oy < Ho) {
#pragma unroll
        for (int c2 = 0; c2 < COT; ++c2) {
            const int co = cog * COT + c2;
            float* obase = out + ((size_t)(nb * CO + co) * Ho + oy) * Wo;
#pragma unroll
            for (int p = 0; p < P; ++p) {
                int x = x0 + p;
                if (x < Wo) obase[x] = acc[c2][p];
            }
        }
    }
}

extern "C" void kernel_launch(void* const* d_in, const int* in_sizes, int n_in,
                              void* d_out, int out_size, void* d_ws, size_t ws_size,
                              hipStream_t stream) {
    const float* x = (const float*)d_in[0];
    float* out = (float*)d_out;
    float* ws = (float*)d_ws;

    static const int CiA[10]  = {1, 4, 8, 16, 16, 8, 16, 16, 8, 4};
    static const int CoA[10]  = {4, 8, 16, 16, 8, 16, 16, 8, 4, 1};
    static const int KA[10]   = {3, 3, 3, 2, 2, 2, 2, 3, 3, 3};
    static const int PREPAD[10] = {0, 0, 0, 0, 0, 2, 2, 4, 4, 4};

    int wnoff[11]; wnoff[0] = 0;
    for (int l = 0; l < 10; ++l)
        wnoff[l + 1] = wnoff[l] + CoA[l] * CiA[l] * KA[l] * KA[l];

    float* wn = ws;                       // softmaxed weights (< 8192 floats)
    const size_t BUF = 6900000;
    float* bufA = ws + 8192;
    float* bufB = bufA + BUF;

    WP wp;
    for (int l = 0; l < 10; ++l) {
        wp.src[l] = (const float*)d_in[1 + l];
        wp.dst[l] = wn + wnoff[l];
        wp.Co[l] = CoA[l];
        wp.n[l] = CiA[l] * KA[l] * KA[l];
    }
    softmax_all<<<10, 64, 0, stream>>>(wp);

    const int NB = 48;                    // 6 comps * 8 batch
    const int NMAT = 8 * 96 * 96;
    logm_k<<<(NMAT + 255) / 256, 256, 0, stream>>>(x, bufA, NMAT);

    float* cur = bufA;
    float* nxt = bufB;
    int H = 96, W = 96;                   // stored dims of cur

#define RUN_LAYER(L, CI_, CO_, K_)                                          \
    {                                                                       \
        int pad = PREPAD[L];                                                \
        int Hv = H + pad, Wv = W + pad;                                     \
        int Ho = Hv - K_ + 1, Wo = Wv - K_ + 1;                             \
        constexpr int COT_ = (CO_ < 4) ? CO_ : 4;                           \
        dim3 blk(16, 16);                                                   \
        dim3 grd((Wo + 31) / 32, (Ho + 15) / 16, NB * (CO_ / COT_));        \
        conv_tile<CI_, CO_, K_><<<grd, blk, 0, stream>>>(                   \
            cur, nxt, wn + wnoff[L], H, W, pad);                            \
        { float* t = cur; cur = nxt; nxt = t; }                             \
        H = Ho; W = Wo;                                                     \
    }

    RUN_LAYER(0, 1, 4, 3)
    RUN_LAYER(1, 4, 8, 3)
    RUN_LAYER(2, 8, 16, 3)
    RUN_LAYER(3, 16, 16, 2)
    RUN_LAYER(4, 16, 8, 2)
    RUN_LAYER(5, 8, 16, 2)
    RUN_LAYER(6, 16, 16, 2)
    RUN_LAYER(7, 16, 8, 3)
    RUN_LAYER(8, 8, 4, 3)
    RUN_LAYER(9, 4, 1, 3)
#undef RUN_LAYER

    expm_k<<<(NMAT + 255) / 256, 256, 0, stream>>>(cur, out, NMAT);
}

// Round 4
// 327.316 us; speedup vs baseline: 4.0165x; 1.2087x over previous
//
#include <hip/hip_runtime.h>
#include <math.h>

// ---------------------------------------------------------------------------
// ManifoldNet SPD network, fused in log-domain.
// logm(x) once -> 10 convs (zero-pad fused into staging) on the 6 unique
// components of the symmetric log field (treated as batch) -> expm once.
// Conv v4: LDS input tile staged ONCE for ALL output channels (NG=1);
// weights via wave-uniform scalar loads (SGPR operands, zero VGPR cost).
// ---------------------------------------------------------------------------

#define DEVFN __device__ __forceinline__

DEVFN void jrot(float A[3][3], float V[3][3], int p, int q) {
    float apq = A[p][q];
    if (fabsf(apq) < 1e-30f) return;
    float app = A[p][p], aqq = A[q][q];
    float tau = (aqq - app) / (2.0f * apq);
    float t = copysignf(1.0f, tau) / (fabsf(tau) + sqrtf(1.0f + tau * tau));
    float c = rsqrtf(1.0f + t * t);
    float s = t * c;
    int r = 3 - p - q;
    float arp = A[r][p], arq = A[r][q];
    A[p][p] = app - t * apq;
    A[q][q] = aqq + t * apq;
    A[p][q] = 0.0f; A[q][p] = 0.0f;
    A[r][p] = c * arp - s * arq; A[p][r] = A[r][p];
    A[r][q] = s * arp + c * arq; A[q][r] = A[r][q];
#pragma unroll
    for (int i = 0; i < 3; ++i) {
        float vip = V[i][p], viq = V[i][q];
        V[i][p] = c * vip - s * viq;
        V[i][q] = s * vip + c * viq;
    }
}

DEVFN void eigh3(float A[3][3], float V[3][3]) {
    V[0][0] = 1.f; V[0][1] = 0.f; V[0][2] = 0.f;
    V[1][0] = 0.f; V[1][1] = 1.f; V[1][2] = 0.f;
    V[2][0] = 0.f; V[2][1] = 0.f; V[2][2] = 1.f;
#pragma unroll
    for (int s = 0; s < 6; ++s) {
        jrot(A, V, 0, 1);
        jrot(A, V, 0, 2);
        jrot(A, V, 1, 2);
    }
}

// x: [n,3,3] SPD (f32). out: planar [6][n], comps (00,01,02,11,12,22).
__global__ void logm_k(const float* __restrict__ x, float* __restrict__ out, int n) {
    int i = blockIdx.x * blockDim.x + threadIdx.x;
    if (i >= n) return;
    const float* m = x + (size_t)i * 9;
    float a01 = 0.5f * (m[1] + m[3]);
    float a02 = 0.5f * (m[2] + m[6]);
    float a12 = 0.5f * (m[5] + m[7]);
    float A[3][3] = {{m[0], a01, a02}, {a01, m[4], a12}, {a02, a12, m[8]}};
    float V[3][3];
    eigh3(A, V);
    float d0 = logf(fmaxf(A[0][0], 1e-30f));
    float d1 = logf(fmaxf(A[1][1], 1e-30f));
    float d2 = logf(fmaxf(A[2][2], 1e-30f));
    float L00 = V[0][0]*d0*V[0][0] + V[0][1]*d1*V[0][1] + V[0][2]*d2*V[0][2];
    float L01 = V[0][0]*d0*V[1][0] + V[0][1]*d1*V[1][1] + V[0][2]*d2*V[1][2];
    float L02 = V[0][0]*d0*V[2][0] + V[0][1]*d1*V[2][1] + V[0][2]*d2*V[2][2];
    float L11 = V[1][0]*d0*V[1][0] + V[1][1]*d1*V[1][1] + V[1][2]*d2*V[1][2];
    float L12 = V[1][0]*d0*V[2][0] + V[1][1]*d1*V[2][1] + V[1][2]*d2*V[2][2];
    float L22 = V[2][0]*d0*V[2][0] + V[2][1]*d1*V[2][1] + V[2][2]*d2*V[2][2];
    out[0 * (size_t)n + i] = L00;
    out[1 * (size_t)n + i] = L01;
    out[2 * (size_t)n + i] = L02;
    out[3 * (size_t)n + i] = L11;
    out[4 * (size_t)n + i] = L12;
    out[5 * (size_t)n + i] = L22;
}

__global__ void expm_k(const float* __restrict__ Lp, float* __restrict__ out, int n) {
    int i = blockIdx.x * blockDim.x + threadIdx.x;
    if (i >= n) return;
    float a00 = Lp[0 * (size_t)n + i];
    float a01 = Lp[1 * (size_t)n + i];
    float a02 = Lp[2 * (size_t)n + i];
    float a11 = Lp[3 * (size_t)n + i];
    float a12 = Lp[4 * (size_t)n + i];
    float a22 = Lp[5 * (size_t)n + i];
    float A[3][3] = {{a00, a01, a02}, {a01, a11, a12}, {a02, a12, a22}};
    float V[3][3];
    eigh3(A, V);
    float e0 = expf(A[0][0]);
    float e1 = expf(A[1][1]);
    float e2 = expf(A[2][2]);
    float m00 = V[0][0]*e0*V[0][0] + V[0][1]*e1*V[0][1] + V[0][2]*e2*V[0][2];
    float m01 = V[0][0]*e0*V[1][0] + V[0][1]*e1*V[1][1] + V[0][2]*e2*V[1][2];
    float m02 = V[0][0]*e0*V[2][0] + V[0][1]*e1*V[2][1] + V[0][2]*e2*V[2][2];
    float m11 = V[1][0]*e0*V[1][0] + V[1][1]*e1*V[1][1] + V[1][2]*e2*V[1][2];
    float m12 = V[1][0]*e0*V[2][0] + V[1][1]*e1*V[2][1] + V[1][2]*e2*V[2][2];
    float m22 = V[2][0]*e0*V[2][0] + V[2][1]*e1*V[2][1] + V[2][2]*e2*V[2][2];
    float* o = out + (size_t)i * 9;
    o[0] = m00; o[1] = m01; o[2] = m02;
    o[3] = m01; o[4] = m11; o[5] = m12;
    o[6] = m02; o[7] = m12; o[8] = m22;
}

// One kernel for all 10 layer softmaxes: block l = layer l, thread co.
struct WP {
    const float* src[10];
    float* dst[10];
    int Co[10];
    int n[10];
};
__global__ void softmax_all(WP wp) {
    int l = blockIdx.x;
    int co = threadIdx.x;
    if (co >= wp.Co[l]) return;
    int n = wp.n[l];
    const float* src = wp.src[l] + (size_t)co * n;
    float* dst = wp.dst[l] + (size_t)co * n;
    float mx = -1e30f;
    for (int i = 0; i < n; ++i) mx = fmaxf(mx, src[i]);
    float s = 0.f;
    for (int i = 0; i < n; ++i) s += expf(src[i] - mx);
    float inv = 1.0f / s;
    for (int i = 0; i < n; ++i) dst[i] = expf(src[i] - mx) * inv;
}

// ---------------------------------------------------------------------------
// LDS-tiled direct conv on planar [48][C][H][W] log field with fused PRE-pad
// (virtual zero rows/cols: outside [pad, Hin) x [pad, Win) reads 0, matching
// reference identity padding in log-domain).
// Block 16x16. Thread: P=2 x-pixels for ALL CO output channels.
// gridDim.z = 48. Weights read with wave-uniform indices -> SGPR operands.
// ---------------------------------------------------------------------------
template<int CI, int CO, int K>
__global__ __launch_bounds__(256)
void conv_tile(const float* __restrict__ in, float* __restrict__ out,
               const float* __restrict__ wn, int Hin, int Win, int pad) {
    constexpr int P = 2, TH = 16, TW = 32;
    constexpr int CC = (CI > 8) ? 8 : CI;
    constexpr int THI = TH + K - 1;
    constexpr int TWI = TW + K - 1;
    constexpr int ROWW = (TWI + 3) & ~3;

    __shared__ float itile[CC][THI][ROWW];

    const int tx = threadIdx.x, ty = threadIdx.y;
    const int tid = ty * 16 + tx;
    const int Hv = Hin + pad, Wv = Win + pad;
    const int Ho = Hv - K + 1, Wo = Wv - K + 1;
    const int nb = blockIdx.z;
    const int gy0 = blockIdx.y * TH;
    const int gx0 = blockIdx.x * TW;

    float acc[CO][P];
#pragma unroll
    for (int c2 = 0; c2 < CO; ++c2)
#pragma unroll
        for (int p = 0; p < P; ++p) acc[c2][p] = 0.f;

    const int oy = gy0 + ty;
    const int x0 = gx0 + tx * P;

    for (int c0 = 0; c0 < CI; c0 += CC) {
        __syncthreads();
        // stage CC channels of the (virtually padded) input tile
#pragma unroll
        for (int cc = 0; cc < CC; ++cc) {
            const float* ibase = in + ((size_t)(nb * CI + c0 + cc) * Hin) * Win;
            for (int idx = tid; idx < THI * TWI; idx += 256) {
                int r = idx / TWI;
                int c = idx - r * TWI;
                int gy = gy0 + r, gx = gx0 + c;
                float v = 0.f;
                if (gy >= pad && gy < Hin && gx >= pad && gx < Win)
                    v = ibase[(size_t)(gy - pad) * Win + (gx - pad)];
                itile[cc][r][c] = v;
            }
        }
        __syncthreads();
#pragma unroll
        for (int cc = 0; cc < CC; ++cc) {
            const int ci = c0 + cc;
#pragma unroll
            for (int kh = 0; kh < K; ++kh) {
                float2 u0 = *(const float2*)&itile[cc][ty + kh][tx * P];
                float2 u1 = *(const float2*)&itile[cc][ty + kh][tx * P + 2];
                float rv[4] = {u0.x, u0.y, u1.x, u1.y};
#pragma unroll
                for (int c2 = 0; c2 < CO; ++c2) {
                    const float* wb = wn + ((size_t)c2 * CI + ci) * (K * K) + kh * K;
#pragma unroll
                    for (int kw = 0; kw < K; ++kw) {
                        float w = wb[kw];   // uniform -> s_load, SGPR operand
#pragma unroll
                        for (int p = 0; p < P; ++p)
                            acc[c2][p] = fmaf(rv[p + kw], w, acc[c2][p]);
                    }
                }
            }
        }
    }

    if (oy < Ho) {
#pragma unroll
        for (int c2 = 0; c2 < CO; ++c2) {
            float* obase = out + ((size_t)(nb * CO + c2) * Ho + oy) * Wo;
#pragma unroll
            for (int p = 0; p < P; ++p) {
                int x = x0 + p;
                if (x < Wo) obase[x] = acc[c2][p];
            }
        }
    }
}

extern "C" void kernel_launch(void* const* d_in, const int* in_sizes, int n_in,
                              void* d_out, int out_size, void* d_ws, size_t ws_size,
                              hipStream_t stream) {
    const float* x = (const float*)d_in[0];
    float* out = (float*)d_out;
    float* ws = (float*)d_ws;

    static const int CiA[10]  = {1, 4, 8, 16, 16, 8, 16, 16, 8, 4};
    static const int CoA[10]  = {4, 8, 16, 16, 8, 16, 16, 8, 4, 1};
    static const int KA[10]   = {3, 3, 3, 2, 2, 2, 2, 3, 3, 3};
    static const int PREPAD[10] = {0, 0, 0, 0, 0, 2, 2, 4, 4, 4};

    int wnoff[11]; wnoff[0] = 0;
    for (int l = 0; l < 10; ++l)
        wnoff[l + 1] = wnoff[l] + CoA[l] * CiA[l] * KA[l] * KA[l];

    float* wn = ws;                       // softmaxed weights (< 8192 floats)
    const size_t BUF = 6900000;
    float* bufA = ws + 8192;
    float* bufB = bufA + BUF;

    WP wp;
    for (int l = 0; l < 10; ++l) {
        wp.src[l] = (const float*)d_in[1 + l];
        wp.dst[l] = wn + wnoff[l];
        wp.Co[l] = CoA[l];
        wp.n[l] = CiA[l] * KA[l] * KA[l];
    }
    softmax_all<<<10, 64, 0, stream>>>(wp);

    const int NB = 48;                    // 6 comps * 8 batch
    const int NMAT = 8 * 96 * 96;
    logm_k<<<(NMAT + 255) / 256, 256, 0, stream>>>(x, bufA, NMAT);

    float* cur = bufA;
    float* nxt = bufB;
    int H = 96, W = 96;                   // stored dims of cur

#define RUN_LAYER(L, CI_, CO_, K_)                                          \
    {                                                                       \
        int pad = PREPAD[L];                                                \
        int Hv = H + pad, Wv = W + pad;                                     \
        int Ho = Hv - K_ + 1, Wo = Wv - K_ + 1;                             \
        dim3 blk(16, 16);                                                   \
        dim3 grd((Wo + 31) / 32, (Ho + 15) / 16, NB);                       \
        conv_tile<CI_, CO_, K_><<<grd, blk, 0, stream>>>(                   \
            cur, nxt, wn + wnoff[L], H, W, pad);                            \
        { float* t = cur; cur = nxt; nxt = t; }                             \
        H = Ho; W = Wo;                                                     \
    }

    RUN_LAYER(0, 1, 4, 3)
    RUN_LAYER(1, 4, 8, 3)
    RUN_LAYER(2, 8, 16, 3)
    RUN_LAYER(3, 16, 16, 2)
    RUN_LAYER(4, 16, 8, 2)
    RUN_LAYER(5, 8, 16, 2)
    RUN_LAYER(6, 16, 16, 2)
    RUN_LAYER(7, 16, 8, 3)
    RUN_LAYER(8, 8, 4, 3)
    RUN_LAYER(9, 4, 1, 3)
#undef RUN_LAYER

    expm_k<<<(NMAT + 255) / 256, 256, 0, stream>>>(cur, out, NMAT);
}